// Round 1
// baseline (364.250 us; speedup 1.0000x reference)
//
#include <hip/hip_runtime.h>
#include <hip/hip_bf16.h>
#include <math.h>

#define NEGV (-1e10f)

typedef __attribute__((ext_vector_type(8))) short bf16x8;
typedef __attribute__((ext_vector_type(4))) float f32x4;

static __device__ __forceinline__ unsigned short f2bf(float f) {
  unsigned int u = __builtin_bit_cast(unsigned int, f);
  unsigned int r = (u + 0x7fffu + ((u >> 16) & 1u)) >> 16;
  return (unsigned short)r;
}

// ---------------------------------------------------------------------------
// K1: cast emb fp32 -> bf16 AND compute attn-weight logits (dot with w_weight)
// one wave per row of emb [8192 x 768]
// ---------------------------------------------------------------------------
__global__ __launch_bounds__(256) void cast_emb_logits(
    const float* __restrict__ emb, const int* __restrict__ tags,
    const float* __restrict__ ww, unsigned short* __restrict__ embbf,
    float* __restrict__ logits) {
  int w = threadIdx.x >> 6, lane = threadIdx.x & 63;
  int row = blockIdx.x * 4 + w;  // 0..8191
  const float4* src = (const float4*)(emb + (size_t)row * 768);
  const float4* wsrc = (const float4*)ww;
  ushort4* dst = (ushort4*)(embbf + (size_t)row * 768);
  float d = 0.f;
#pragma unroll
  for (int j = 0; j < 3; j++) {
    int idx = lane + 64 * j;  // 192 float4 per row
    float4 v = src[idx];
    float4 wv = wsrc[idx];
    d += v.x * wv.x + v.y * wv.y + v.z * wv.z + v.w * wv.w;
    ushort4 o;
    o.x = f2bf(v.x); o.y = f2bf(v.y); o.z = f2bf(v.z); o.w = f2bf(v.w);
    dst[idx] = o;
  }
#pragma unroll
  for (int off = 32; off; off >>= 1) d += __shfl_xor(d, off);
  if (lane == 0) logits[row] = (tags[row] == 0) ? NEGV : d;
}

// ---------------------------------------------------------------------------
// K2: cast the three weight matrices fp32 -> bf16  [3][768][768]
// ---------------------------------------------------------------------------
__global__ __launch_bounds__(256) void cast_w(
    const float* __restrict__ wq, const float* __restrict__ wk,
    const float* __restrict__ wv, unsigned short* __restrict__ out) {
  int z = blockIdx.y;
  const float* src = (z == 0) ? wq : (z == 1) ? wk : wv;
  int idx = blockIdx.x * 256 + threadIdx.x;  // float4 index, 147456 per matrix
  float4 v = ((const float4*)src)[idx];
  ushort4 o;
  o.x = f2bf(v.x); o.y = f2bf(v.y); o.z = f2bf(v.z); o.w = f2bf(v.w);
  ((ushort4*)(out + (size_t)z * 589824))[idx] = o;
}

// ---------------------------------------------------------------------------
// K3: softmax over s=1024 per batch of the masked logits -> aw
// ---------------------------------------------------------------------------
__global__ __launch_bounds__(256) void softmax_aw(
    const float* __restrict__ logits, float* __restrict__ aw) {
  __shared__ float red[4];
  int b = blockIdx.x, t = threadIdx.x;
  const float* L = logits + b * 1024;
  float x0 = L[t], x1 = L[t + 256], x2 = L[t + 512], x3 = L[t + 768];
  float m = fmaxf(fmaxf(x0, x1), fmaxf(x2, x3));
#pragma unroll
  for (int off = 32; off; off >>= 1) m = fmaxf(m, __shfl_xor(m, off));
  if ((t & 63) == 0) red[t >> 6] = m;
  __syncthreads();
  m = fmaxf(fmaxf(red[0], red[1]), fmaxf(red[2], red[3]));
  float e0 = __expf(x0 - m), e1 = __expf(x1 - m), e2 = __expf(x2 - m),
        e3 = __expf(x3 - m);
  float s = e0 + e1 + e2 + e3;
#pragma unroll
  for (int off = 32; off; off >>= 1) s += __shfl_xor(s, off);
  __syncthreads();
  if ((t & 63) == 0) red[t >> 6] = s;
  __syncthreads();
  float inv = 1.0f / (red[0] + red[1] + red[2] + red[3]);
  float* A = aw + b * 1024;
  A[t] = e0 * inv; A[t + 256] = e1 * inv;
  A[t + 512] = e2 * inv; A[t + 768] = e3 * inv;
}

// ---------------------------------------------------------------------------
// K4: QKV projection GEMM. C[8192,768] = A[8192,768] x W[z][768,768]^T (B^T form)
// z=0 -> Q bf16 permuted (o -> (o&7)*96 + (o>>3)), z=1 -> K same, z=2 -> V fp32
// 128x128 tile, BK=32, 4 waves, each wave 64x64 (4x4 16x16x32 MFMA frags)
// ---------------------------------------------------------------------------
#define ASTR 40  // padded LDS stride in bf16 elements (80B) to spread banks
__global__ __launch_bounds__(256) void qkv_gemm(
    const unsigned short* __restrict__ A, const unsigned short* __restrict__ Wbf,
    unsigned short* __restrict__ Qt, unsigned short* __restrict__ Kt,
    float* __restrict__ V) {
  __shared__ unsigned short As[128 * ASTR];
  __shared__ unsigned short Bs[128 * ASTR];
  int z = blockIdx.z;
  const unsigned short* B = Wbf + (size_t)z * 589824;
  int mb = blockIdx.x * 128, nb = blockIdx.y * 128;
  int tid = threadIdx.x;
  int w = tid >> 6, lane = tid & 63;
  int wm = w >> 1, wn = w & 1;
  int c = lane & 15, quad = lane >> 4;
  f32x4 acc[4][4];
#pragma unroll
  for (int i = 0; i < 4; i++)
#pragma unroll
    for (int j = 0; j < 4; j++) acc[i][j] = 0;

  for (int kb = 0; kb < 768; kb += 32) {
    __syncthreads();
#pragma unroll
    for (int it = 0; it < 2; it++) {
      int s2 = tid + it * 256;          // 512 16B segments per tile
      int row = s2 >> 2, ko = (s2 & 3) * 8;
      *(uint4*)&As[row * ASTR + ko] =
          *(const uint4*)&A[(size_t)(mb + row) * 768 + kb + ko];
      *(uint4*)&Bs[row * ASTR + ko] =
          *(const uint4*)&B[(size_t)(nb + row) * 768 + kb + ko];
    }
    __syncthreads();
    bf16x8 af[4], bfr[4];
#pragma unroll
    for (int i = 0; i < 4; i++)
      af[i] = *(const bf16x8*)&As[(wm * 64 + i * 16 + c) * ASTR + quad * 8];
#pragma unroll
    for (int j = 0; j < 4; j++)
      bfr[j] = *(const bf16x8*)&Bs[(wn * 64 + j * 16 + c) * ASTR + quad * 8];
#pragma unroll
    for (int i = 0; i < 4; i++)
#pragma unroll
      for (int j = 0; j < 4; j++)
        acc[i][j] = __builtin_amdgcn_mfma_f32_16x16x32_bf16(af[i], bfr[j],
                                                            acc[i][j], 0, 0, 0);
  }
  // epilogue: C row = mb+wm*64+i*16+quad*4+r, col = nb+wn*64+j*16+c
  if (z == 2) {
#pragma unroll
    for (int i = 0; i < 4; i++)
#pragma unroll
      for (int j = 0; j < 4; j++)
#pragma unroll
        for (int r = 0; r < 4; r++) {
          int rowg = mb + wm * 64 + i * 16 + quad * 4 + r;
          int colg = nb + wn * 64 + j * 16 + c;
          V[(size_t)rowg * 768 + colg] = acc[i][j][r];
        }
  } else {
    unsigned short* O = (z == 0) ? Qt : Kt;
#pragma unroll
    for (int i = 0; i < 4; i++)
#pragma unroll
      for (int j = 0; j < 4; j++)
#pragma unroll
        for (int r = 0; r < 4; r++) {
          int rowg = mb + wm * 64 + i * 16 + quad * 4 + r;
          int o = nb + wn * 64 + j * 16 + c;
          int o2 = (o & 7) * 96 + (o >> 3);  // head-major within row
          O[(size_t)rowg * 768 + o2] = f2bf(acc[i][j][r]);
        }
  }
}

// ---------------------------------------------------------------------------
// K5: attention scores + head-softmax + aw-weighted accumulation into Pt[b,k,h]
// block = 32q x 32k tile, 4 waves: wave w -> (qsub=w>>1, ksub=w&1) 16x16, all 8 h
// ---------------------------------------------------------------------------
__global__ __launch_bounds__(256) void attn(
    const unsigned short* __restrict__ Qt, const unsigned short* __restrict__ Kt,
    const float* __restrict__ aw, float* __restrict__ Pt) {
  int b = blockIdx.z;
  int q0 = blockIdx.y * 32, k0 = blockIdx.x * 32;
  int tid = threadIdx.x;
  int w = tid >> 6, lane = tid & 63;
  int qsub = w >> 1, ksub = w & 1;
  int c = lane & 15, quad = lane >> 4;
  const unsigned short* Qp =
      Qt + (size_t)(b * 1024 + q0 + qsub * 16 + c) * 768 + quad * 8;
  const unsigned short* Kp =
      Kt + (size_t)(b * 1024 + k0 + ksub * 16 + c) * 768 + quad * 8;
  f32x4 s[8];
#pragma unroll
  for (int h = 0; h < 8; h++) {
    f32x4 sh = 0;
#pragma unroll
    for (int t = 0; t < 3; t++) {
      bf16x8 a = *(const bf16x8*)(Qp + h * 96 + t * 32);
      bf16x8 kf = *(const bf16x8*)(Kp + h * 96 + t * 32);
      sh = __builtin_amdgcn_mfma_f32_16x16x32_bf16(a, kf, sh, 0, 0, 0);
    }
    s[h] = sh;
  }
  const float scale = 0.10206207261596577f;  // 1/sqrt(96)
  float partial[8];
#pragma unroll
  for (int h = 0; h < 8; h++) partial[h] = 0.f;
  const float* awb = aw + b * 1024 + q0 + qsub * 16 + quad * 4;
#pragma unroll
  for (int r = 0; r < 4; r++) {
    float v[8];
    float m = -1e30f;
#pragma unroll
    for (int h = 0; h < 8; h++) {
      v[h] = s[h][r] * scale;
      m = fmaxf(m, v[h]);
    }
    float ssum = 0.f;
#pragma unroll
    for (int h = 0; h < 8; h++) {
      float e = __expf(v[h] - m);
      v[h] = e;
      ssum += e;
    }
    float g = awb[r] / ssum;  // aw==0 exactly for padded queries
#pragma unroll
    for (int h = 0; h < 8; h++) partial[h] += v[h] * g;
  }
#pragma unroll
  for (int h = 0; h < 8; h++) {
    float v = partial[h];
    v += __shfl_xor(v, 16);
    v += __shfl_xor(v, 32);
    if (lane < 16)
      atomicAdd(&Pt[(size_t)(b * 1024 + k0 + ksub * 16 + lane) * 8 + h], v);
  }
}

// ---------------------------------------------------------------------------
// K6: out[b,o] = sum_k Pt[b,k,o&7] * V[b,k,o]
// ---------------------------------------------------------------------------
__global__ __launch_bounds__(256) void finalize(
    const float* __restrict__ Pt, const float* __restrict__ V,
    float* __restrict__ out) {
  int kc = blockIdx.x, b = blockIdx.y;
  int t = threadIdx.x;
  int h = t & 7;
  float a0 = 0, a1 = 0, a2 = 0;
  const float* Vb = V + (size_t)b * 1024 * 768;
  for (int kk = 0; kk < 64; kk++) {
    int k = kc * 64 + kk;
    float p = Pt[(size_t)(b * 1024 + k) * 8 + h];
    const float* vr = Vb + (size_t)k * 768;
    a0 += p * vr[t];
    a1 += p * vr[t + 256];
    a2 += p * vr[t + 512];
  }
  atomicAdd(&out[b * 768 + t], a0);
  atomicAdd(&out[b * 768 + t + 256], a1);
  atomicAdd(&out[b * 768 + t + 512], a2);
}

// ---------------------------------------------------------------------------
extern "C" void kernel_launch(void* const* d_in, const int* in_sizes, int n_in,
                              void* d_out, int out_size, void* d_ws,
                              size_t ws_size, hipStream_t stream) {
  const float* emb = (const float*)d_in[0];
  const int* tags = (const int*)d_in[1];
  const float* ww = (const float*)d_in[2];
  const float* wq = (const float*)d_in[3];
  const float* wk = (const float*)d_in[4];
  const float* wv = (const float*)d_in[5];
  float* out = (float*)d_out;
  char* ws = (char*)d_ws;
  // ws layout (bytes, all 256-aligned):
  unsigned short* embbf = (unsigned short*)(ws + 0);           // 12,582,912
  unsigned short* wbf   = (unsigned short*)(ws + 12582912);    //  3,538,944
  unsigned short* Qt    = (unsigned short*)(ws + 16121856);    // 12,582,912
  unsigned short* Kt    = (unsigned short*)(ws + 28704768);    // 12,582,912
  float* V              = (float*)(ws + 41287680);             // 25,165,824
  float* logits         = (float*)(ws + 66453504);             //     32,768
  float* aw             = (float*)(ws + 66486272);             //     32,768
  float* Pt             = (float*)(ws + 66519040);             //    262,144

  hipMemsetAsync(Pt, 0, 8 * 1024 * 8 * sizeof(float), stream);
  hipMemsetAsync(out, 0, 8 * 768 * sizeof(float), stream);
  cast_emb_logits<<<2048, 256, 0, stream>>>(emb, tags, ww, embbf, logits);
  cast_w<<<dim3(576, 3), 256, 0, stream>>>(wq, wk, wv, wbf);
  softmax_aw<<<8, 256, 0, stream>>>(logits, aw);
  qkv_gemm<<<dim3(64, 6, 3), 256, 0, stream>>>(embbf, wbf, Qt, Kt, V);
  attn<<<dim3(32, 32, 8), 256, 0, stream>>>(Qt, Kt, aw, Pt);
  finalize<<<dim3(16, 8), 256, 0, stream>>>(Pt, V, out);
}

// Round 2
// 293.687 us; speedup vs baseline: 1.2403x; 1.2403x over previous
//
#include <hip/hip_runtime.h>
#include <hip/hip_bf16.h>
#include <math.h>

#define NEGV (-1e10f)

typedef __attribute__((ext_vector_type(8))) short bf16x8;
typedef __attribute__((ext_vector_type(4))) float f32x4;

static __device__ __forceinline__ unsigned short f2bf(float f) {
  unsigned int u = __builtin_bit_cast(unsigned int, f);
  unsigned int r = (u + 0x7fffu + ((u >> 16) & 1u)) >> 16;
  return (unsigned short)r;
}

// ---------------------------------------------------------------------------
// K1: cast emb fp32 -> bf16 AND compute attn-weight logits (dot with w_weight)
// ---------------------------------------------------------------------------
__global__ __launch_bounds__(256) void cast_emb_logits(
    const float* __restrict__ emb, const int* __restrict__ tags,
    const float* __restrict__ ww, unsigned short* __restrict__ embbf,
    float* __restrict__ logits) {
  int w = threadIdx.x >> 6, lane = threadIdx.x & 63;
  int row = blockIdx.x * 4 + w;  // 0..8191
  const float4* src = (const float4*)(emb + (size_t)row * 768);
  const float4* wsrc = (const float4*)ww;
  ushort4* dst = (ushort4*)(embbf + (size_t)row * 768);
  float d = 0.f;
#pragma unroll
  for (int j = 0; j < 3; j++) {
    int idx = lane + 64 * j;
    float4 v = src[idx];
    float4 wv = wsrc[idx];
    d += v.x * wv.x + v.y * wv.y + v.z * wv.z + v.w * wv.w;
    ushort4 o;
    o.x = f2bf(v.x); o.y = f2bf(v.y); o.z = f2bf(v.z); o.w = f2bf(v.w);
    dst[idx] = o;
  }
#pragma unroll
  for (int off = 32; off; off >>= 1) d += __shfl_xor(d, off);
  if (lane == 0) logits[row] = (tags[row] == 0) ? NEGV : d;
}

// ---------------------------------------------------------------------------
// K2: cast the three weight matrices fp32 -> bf16  [3][768][768]
// ---------------------------------------------------------------------------
__global__ __launch_bounds__(256) void cast_w(
    const float* __restrict__ wq, const float* __restrict__ wk,
    const float* __restrict__ wv, unsigned short* __restrict__ out) {
  int z = blockIdx.y;
  const float* src = (z == 0) ? wq : (z == 1) ? wk : wv;
  int idx = blockIdx.x * 256 + threadIdx.x;
  float4 v = ((const float4*)src)[idx];
  ushort4 o;
  o.x = f2bf(v.x); o.y = f2bf(v.y); o.z = f2bf(v.z); o.w = f2bf(v.w);
  ((ushort4*)(out + (size_t)z * 589824))[idx] = o;
}

// ---------------------------------------------------------------------------
// K3: softmax over s=1024 per batch of the masked logits -> aw
// ---------------------------------------------------------------------------
__global__ __launch_bounds__(256) void softmax_aw(
    const float* __restrict__ logits, float* __restrict__ aw) {
  __shared__ float red[4];
  int b = blockIdx.x, t = threadIdx.x;
  const float* L = logits + b * 1024;
  float x0 = L[t], x1 = L[t + 256], x2 = L[t + 512], x3 = L[t + 768];
  float m = fmaxf(fmaxf(x0, x1), fmaxf(x2, x3));
#pragma unroll
  for (int off = 32; off; off >>= 1) m = fmaxf(m, __shfl_xor(m, off));
  if ((t & 63) == 0) red[t >> 6] = m;
  __syncthreads();
  m = fmaxf(fmaxf(red[0], red[1]), fmaxf(red[2], red[3]));
  float e0 = __expf(x0 - m), e1 = __expf(x1 - m), e2 = __expf(x2 - m),
        e3 = __expf(x3 - m);
  float s = e0 + e1 + e2 + e3;
#pragma unroll
  for (int off = 32; off; off >>= 1) s += __shfl_xor(s, off);
  __syncthreads();
  if ((t & 63) == 0) red[t >> 6] = s;
  __syncthreads();
  float inv = 1.0f / (red[0] + red[1] + red[2] + red[3]);
  float* A = aw + b * 1024;
  A[t] = e0 * inv; A[t + 256] = e1 * inv;
  A[t + 512] = e2 * inv; A[t + 768] = e3 * inv;
}

// ---------------------------------------------------------------------------
// K4: QKV projection GEMM. C[8192,768] = A[8192,768] x W[z][768,768]^T
// z=0 -> Q fragment-major bf16, z=1 -> K fragment-major bf16, z=2 -> V fp32
// Fragment-major: element (b,q,h,d) at
//   ((((b*64+q/16)*8+h)*3 + d/32)*64 + (q%16 | ((d/8)%4)<<4))*8 + d%8
// so an attn wave's 16B/lane fragment load is 1KB contiguous.
// ---------------------------------------------------------------------------
#define ASTR 40  // padded LDS stride (bf16 elems) to spread banks
__global__ __launch_bounds__(256) void qkv_gemm(
    const unsigned short* __restrict__ A, const unsigned short* __restrict__ Wbf,
    unsigned short* __restrict__ Qf, unsigned short* __restrict__ Kf,
    float* __restrict__ V) {
  __shared__ unsigned short As[128 * ASTR];
  __shared__ unsigned short Bs[128 * ASTR];
  int z = blockIdx.z;
  const unsigned short* B = Wbf + (size_t)z * 589824;
  int mb = blockIdx.x * 128, nb = blockIdx.y * 128;
  int tid = threadIdx.x;
  int w = tid >> 6, lane = tid & 63;
  int wm = w >> 1, wn = w & 1;
  int c = lane & 15, quad = lane >> 4;
  f32x4 acc[4][4];
#pragma unroll
  for (int i = 0; i < 4; i++)
#pragma unroll
    for (int j = 0; j < 4; j++) acc[i][j] = 0;

  for (int kb = 0; kb < 768; kb += 32) {
    __syncthreads();
#pragma unroll
    for (int it = 0; it < 2; it++) {
      int s2 = tid + it * 256;
      int row = s2 >> 2, ko = (s2 & 3) * 8;
      *(uint4*)&As[row * ASTR + ko] =
          *(const uint4*)&A[(size_t)(mb + row) * 768 + kb + ko];
      *(uint4*)&Bs[row * ASTR + ko] =
          *(const uint4*)&B[(size_t)(nb + row) * 768 + kb + ko];
    }
    __syncthreads();
    bf16x8 af[4], bfr[4];
#pragma unroll
    for (int i = 0; i < 4; i++)
      af[i] = *(const bf16x8*)&As[(wm * 64 + i * 16 + c) * ASTR + quad * 8];
#pragma unroll
    for (int j = 0; j < 4; j++)
      bfr[j] = *(const bf16x8*)&Bs[(wn * 64 + j * 16 + c) * ASTR + quad * 8];
#pragma unroll
    for (int i = 0; i < 4; i++)
#pragma unroll
      for (int j = 0; j < 4; j++)
        acc[i][j] = __builtin_amdgcn_mfma_f32_16x16x32_bf16(af[i], bfr[j],
                                                            acc[i][j], 0, 0, 0);
  }
  // C row = mb+wm*64+i*16+quad*4+r, col = nb+wn*64+j*16+c
  if (z == 2) {
#pragma unroll
    for (int i = 0; i < 4; i++)
#pragma unroll
      for (int j = 0; j < 4; j++)
#pragma unroll
        for (int r = 0; r < 4; r++) {
          int rowg = mb + wm * 64 + i * 16 + quad * 4 + r;
          int colg = nb + wn * 64 + j * 16 + c;
          V[(size_t)rowg * 768 + colg] = acc[i][j][r];
        }
  } else {
    unsigned short* O = (z == 0) ? Qf : Kf;
#pragma unroll
    for (int i = 0; i < 4; i++)
#pragma unroll
      for (int j = 0; j < 4; j++)
#pragma unroll
        for (int r = 0; r < 4; r++) {
          int rowg = mb + wm * 64 + i * 16 + quad * 4 + r;
          int o = nb + wn * 64 + j * 16 + c;
          int bq = rowg >> 10, q = rowg & 1023;
          int h = o & 7, dd = o >> 3;  // head, depth (0..95)
          size_t addr =
              ((((size_t)(bq * 64 + (q >> 4)) * 8 + h) * 3 + (dd >> 5)) * 64 +
               ((q & 15) | (((dd >> 3) & 3) << 4))) * 8 + (dd & 7);
          O[addr] = f2bf(acc[i][j][r]);
        }
  }
}

// ---------------------------------------------------------------------------
// K5: attention, k-stationary. Wave owns one 16-k tile: K frags resident in
// regs; loops 8 q-tiles (q-chunk = 128 q), accumulates aw-weighted
// head-softmax into partial[8]; one plain store per (qc,b,k,h). No atomics.
// grid (16 kb, 8 qc, 8 b), block 256 (4 waves = 4 k-tiles)
// ---------------------------------------------------------------------------
__global__ __launch_bounds__(256) void attn(
    const unsigned short* __restrict__ Qf, const unsigned short* __restrict__ Kf,
    const float* __restrict__ aw, float* __restrict__ Ptp) {
  int b = blockIdx.z;
  int qc = blockIdx.y;
  int kt = blockIdx.x * 4 + (threadIdx.x >> 6);  // k-tile 0..63
  int lane = threadIdx.x & 63;
  int quad = lane >> 4;
  const unsigned short* Kb =
      Kf + (size_t)(b * 64 + kt) * 12288 + (size_t)lane * 8;
  bf16x8 kfr[8][3];
#pragma unroll
  for (int h = 0; h < 8; h++)
#pragma unroll
    for (int t = 0; t < 3; t++)
      kfr[h][t] = *(const bf16x8*)(Kb + (h * 3 + t) * 512);
  float partial[8];
#pragma unroll
  for (int h = 0; h < 8; h++) partial[h] = 0.f;
  const float scale = 0.10206207261596577f;  // 1/sqrt(96)
  for (int qi = 0; qi < 8; qi++) {
    int qt = qc * 8 + qi;
    const unsigned short* Qb =
        Qf + (size_t)(b * 64 + qt) * 12288 + (size_t)lane * 8;
    f32x4 s[8];
#pragma unroll
    for (int h = 0; h < 8; h++) {
      f32x4 sh = 0;
#pragma unroll
      for (int t = 0; t < 3; t++) {
        bf16x8 qfr = *(const bf16x8*)(Qb + (h * 3 + t) * 512);
        sh = __builtin_amdgcn_mfma_f32_16x16x32_bf16(qfr, kfr[h][t], sh, 0, 0, 0);
      }
      s[h] = sh;
    }
    f32x4 al = *(const f32x4*)(aw + b * 1024 + qt * 16 + quad * 4);
#pragma unroll
    for (int r = 0; r < 4; r++) {
      float v[8], m = -1e30f;
#pragma unroll
      for (int h = 0; h < 8; h++) {
        v[h] = s[h][r] * scale;
        m = fmaxf(m, v[h]);
      }
      float ssum = 0.f;
#pragma unroll
      for (int h = 0; h < 8; h++) {
        float e = __expf(v[h] - m);
        v[h] = e;
        ssum += e;
      }
      float g = al[r] / ssum;  // aw==0 exactly for padded queries
#pragma unroll
      for (int h = 0; h < 8; h++) partial[h] += v[h] * g;
    }
  }
#pragma unroll
  for (int h = 0; h < 8; h++) {
    float v = partial[h];
    v += __shfl_xor(v, 16);
    v += __shfl_xor(v, 32);
    partial[h] = v;
  }
  if (lane < 16) {
#pragma unroll
    for (int h = 0; h < 8; h++)
      Ptp[(((size_t)qc * 8 + b) * 1024 + kt * 16 + lane) * 8 + h] = partial[h];
  }
}

// ---------------------------------------------------------------------------
// K6: out[b,o] = sum_k (sum_qc Ptp[qc][b][k][o&7]) * V[b,k,o]
// grid (8 kc, 8 b)
// ---------------------------------------------------------------------------
__global__ __launch_bounds__(256) void finalize(
    const float* __restrict__ Ptp, const float* __restrict__ V,
    float* __restrict__ out) {
  __shared__ float ps[1024];  // 128 k x 8 h
  int kc = blockIdx.x, b = blockIdx.y;
  int t = threadIdx.x;
#pragma unroll
  for (int j = 0; j < 4; j++) {
    int idx = t + j * 256;
    int k = kc * 128 + (idx >> 3), h = idx & 7;
    float s = 0.f;
#pragma unroll
    for (int qc = 0; qc < 8; qc++)
      s += Ptp[(((size_t)qc * 8 + b) * 1024 + k) * 8 + h];
    ps[idx] = s;
  }
  __syncthreads();
  int h = t & 7;
  float a0 = 0, a1 = 0, a2 = 0;
  const float* Vb = V + ((size_t)b * 1024 + kc * 128) * 768;
  for (int kk = 0; kk < 128; kk++) {
    float p = ps[kk * 8 + h];
    const float* vr = Vb + (size_t)kk * 768;
    a0 += p * vr[t];
    a1 += p * vr[t + 256];
    a2 += p * vr[t + 512];
  }
  atomicAdd(&out[b * 768 + t], a0);
  atomicAdd(&out[b * 768 + t + 256], a1);
  atomicAdd(&out[b * 768 + t + 512], a2);
}

// ---------------------------------------------------------------------------
extern "C" void kernel_launch(void* const* d_in, const int* in_sizes, int n_in,
                              void* d_out, int out_size, void* d_ws,
                              size_t ws_size, hipStream_t stream) {
  const float* emb = (const float*)d_in[0];
  const int* tags = (const int*)d_in[1];
  const float* ww = (const float*)d_in[2];
  const float* wq = (const float*)d_in[3];
  const float* wk = (const float*)d_in[4];
  const float* wv = (const float*)d_in[5];
  float* out = (float*)d_out;
  char* ws = (char*)d_ws;
  unsigned short* embbf = (unsigned short*)(ws + 0);           // 12,582,912
  unsigned short* wbf   = (unsigned short*)(ws + 12582912);    //  3,538,944
  unsigned short* Qf    = (unsigned short*)(ws + 16121856);    // 12,582,912
  unsigned short* Kf    = (unsigned short*)(ws + 28704768);    // 12,582,912
  float* V              = (float*)(ws + 41287680);             // 25,165,824
  float* logits         = (float*)(ws + 66453504);             //     32,768
  float* aw             = (float*)(ws + 66486272);             //     32,768
  float* Ptp            = (float*)(ws + 66519040);             //  2,097,152

  hipMemsetAsync(out, 0, 8 * 768 * sizeof(float), stream);
  cast_emb_logits<<<2048, 256, 0, stream>>>(emb, tags, ww, embbf, logits);
  cast_w<<<dim3(576, 3), 256, 0, stream>>>(wq, wk, wv, wbf);
  softmax_aw<<<8, 256, 0, stream>>>(logits, aw);
  qkv_gemm<<<dim3(64, 6, 3), 256, 0, stream>>>(embbf, wbf, Qf, Kf, V);
  attn<<<dim3(16, 8, 8), 256, 0, stream>>>(Qf, Kf, aw, Ptp);
  finalize<<<dim3(8, 8), 256, 0, stream>>>(Ptp, V, out);
}

// Round 3
// 248.155 us; speedup vs baseline: 1.4678x; 1.1835x over previous
//
#include <hip/hip_runtime.h>
#include <hip/hip_bf16.h>
#include <math.h>

#define NEGV (-1e10f)

typedef __attribute__((ext_vector_type(8))) short bf16x8;
typedef __attribute__((ext_vector_type(4))) float f32x4;

static __device__ __forceinline__ unsigned short f2bf(float f) {
  unsigned int u = __builtin_bit_cast(unsigned int, f);
  unsigned int r = (u + 0x7fffu + ((u >> 16) & 1u)) >> 16;
  return (unsigned short)r;
}
static __device__ __forceinline__ float bf2f(unsigned short v) {
  return __builtin_bit_cast(float, (unsigned int)v << 16);
}

#define GLD16(g, l)                                                   \
  __builtin_amdgcn_global_load_lds(                                   \
      (const __attribute__((address_space(1))) void*)(g),             \
      (__attribute__((address_space(3))) void*)(l), 16, 0, 0)

// ---------------------------------------------------------------------------
// K1: cast emb fp32 -> bf16 AND compute attn-weight logits (dot with w_weight)
// ---------------------------------------------------------------------------
__global__ __launch_bounds__(256) void cast_emb_logits(
    const float* __restrict__ emb, const int* __restrict__ tags,
    const float* __restrict__ ww, unsigned short* __restrict__ embbf,
    float* __restrict__ logits) {
  int w = threadIdx.x >> 6, lane = threadIdx.x & 63;
  int row = blockIdx.x * 4 + w;  // 0..8191
  const float4* src = (const float4*)(emb + (size_t)row * 768);
  const float4* wsrc = (const float4*)ww;
  ushort4* dst = (ushort4*)(embbf + (size_t)row * 768);
  float d = 0.f;
#pragma unroll
  for (int j = 0; j < 3; j++) {
    int idx = lane + 64 * j;
    float4 v = src[idx];
    float4 wv = wsrc[idx];
    d += v.x * wv.x + v.y * wv.y + v.z * wv.z + v.w * wv.w;
    ushort4 o;
    o.x = f2bf(v.x); o.y = f2bf(v.y); o.z = f2bf(v.z); o.w = f2bf(v.w);
    dst[idx] = o;
  }
#pragma unroll
  for (int off = 32; off; off >>= 1) d += __shfl_xor(d, off);
  if (lane == 0) logits[row] = (tags[row] == 0) ? NEGV : d;
}

// ---------------------------------------------------------------------------
// K2: cast the three weight matrices fp32 -> bf16  [3][768][768]
// ---------------------------------------------------------------------------
__global__ __launch_bounds__(256) void cast_w(
    const float* __restrict__ wq, const float* __restrict__ wk,
    const float* __restrict__ wv, unsigned short* __restrict__ out) {
  int z = blockIdx.y;
  const float* src = (z == 0) ? wq : (z == 1) ? wk : wv;
  int idx = blockIdx.x * 256 + threadIdx.x;
  float4 v = ((const float4*)src)[idx];
  ushort4 o;
  o.x = f2bf(v.x); o.y = f2bf(v.y); o.z = f2bf(v.z); o.w = f2bf(v.w);
  ((ushort4*)(out + (size_t)z * 589824))[idx] = o;
}

// ---------------------------------------------------------------------------
// K3: softmax over s=1024 per batch of the masked logits -> aw
// ---------------------------------------------------------------------------
__global__ __launch_bounds__(256) void softmax_aw(
    const float* __restrict__ logits, float* __restrict__ aw) {
  __shared__ float red[4];
  int b = blockIdx.x, t = threadIdx.x;
  const float* L = logits + b * 1024;
  float x0 = L[t], x1 = L[t + 256], x2 = L[t + 512], x3 = L[t + 768];
  float m = fmaxf(fmaxf(x0, x1), fmaxf(x2, x3));
#pragma unroll
  for (int off = 32; off; off >>= 1) m = fmaxf(m, __shfl_xor(m, off));
  if ((t & 63) == 0) red[t >> 6] = m;
  __syncthreads();
  m = fmaxf(fmaxf(red[0], red[1]), fmaxf(red[2], red[3]));
  float e0 = __expf(x0 - m), e1 = __expf(x1 - m), e2 = __expf(x2 - m),
        e3 = __expf(x3 - m);
  float s = e0 + e1 + e2 + e3;
#pragma unroll
  for (int off = 32; off; off >>= 1) s += __shfl_xor(s, off);
  __syncthreads();
  if ((t & 63) == 0) red[t >> 6] = s;
  __syncthreads();
  float inv = 1.0f / (red[0] + red[1] + red[2] + red[3]);
  float* A = aw + b * 1024;
  A[t] = e0 * inv; A[t + 256] = e1 * inv;
  A[t + 512] = e2 * inv; A[t + 768] = e3 * inv;
}

// ---------------------------------------------------------------------------
// K4: QKV projection GEMM, m97 structure: 128x128 tile, BK=32, unpadded LDS,
// global_load_lds width=16 staging, 2-barrier K-loop.
// z=0 -> Q fragment-major bf16, z=1 -> K fragment-major bf16, z=2 -> V bf16
// Fragment-major: element (b,q,h,d) at
//   ((((b*64+q/16)*8+h)*3 + d/32)*64 + (q%16 | ((d/8)%4)<<4))*8 + d%8
// ---------------------------------------------------------------------------
__global__ __launch_bounds__(256) void qkv_gemm(
    const unsigned short* __restrict__ A, const unsigned short* __restrict__ Wbf,
    unsigned short* __restrict__ Qf, unsigned short* __restrict__ Kf,
    unsigned short* __restrict__ Vbf) {
  __shared__ unsigned short As[128 * 32];
  __shared__ unsigned short Bs[128 * 32];
  int z = blockIdx.z;
  const unsigned short* B = Wbf + (size_t)z * 589824;
  int mb = blockIdx.x * 128, nb = blockIdx.y * 128;
  int tid = threadIdx.x;
  int w = tid >> 6, lane = tid & 63;
  int wm = w >> 1, wn = w & 1;
  int c = lane & 15, quad = lane >> 4;
  // staging: wave w covers rows [w*32, w*32+32); lane -> row w*32+call*16+lane/4,
  // in-row 16B chunk lane%4. HW writes LDS at (uniform base) + lane*16.
  int lrow = lane >> 2, lcol = (lane & 3) * 8;
  const unsigned short* Ag = A + (size_t)(mb + w * 32 + lrow) * 768 + lcol;
  const unsigned short* Bg = B + (size_t)(nb + w * 32 + lrow) * 768 + lcol;
  unsigned short* AsW = &As[(w * 32) * 32];
  unsigned short* BsW = &Bs[(w * 32) * 32];

  f32x4 acc[4][4];
#pragma unroll
  for (int i = 0; i < 4; i++)
#pragma unroll
    for (int j = 0; j < 4; j++) acc[i][j] = 0;

  for (int kb = 0; kb < 768; kb += 32) {
    GLD16(Ag + kb, AsW);
    GLD16(Ag + kb + (size_t)16 * 768, AsW + 16 * 32);
    GLD16(Bg + kb, BsW);
    GLD16(Bg + kb + (size_t)16 * 768, BsW + 16 * 32);
    __syncthreads();  // drains vmcnt -> staging visible
    bf16x8 af[4], bfr[4];
#pragma unroll
    for (int i = 0; i < 4; i++)
      af[i] = *(const bf16x8*)&As[(wm * 64 + i * 16 + c) * 32 + quad * 8];
#pragma unroll
    for (int j = 0; j < 4; j++)
      bfr[j] = *(const bf16x8*)&Bs[(wn * 64 + j * 16 + c) * 32 + quad * 8];
#pragma unroll
    for (int i = 0; i < 4; i++)
#pragma unroll
      for (int j = 0; j < 4; j++)
        acc[i][j] = __builtin_amdgcn_mfma_f32_16x16x32_bf16(af[i], bfr[j],
                                                            acc[i][j], 0, 0, 0);
    __syncthreads();  // all reads done before next stage overwrites
  }
  // C row = mb+wm*64+i*16+quad*4+r, col = nb+wn*64+j*16+c
  if (z == 2) {
#pragma unroll
    for (int i = 0; i < 4; i++)
#pragma unroll
      for (int j = 0; j < 4; j++)
#pragma unroll
        for (int r = 0; r < 4; r++) {
          int rowg = mb + wm * 64 + i * 16 + quad * 4 + r;
          int colg = nb + wn * 64 + j * 16 + c;
          Vbf[(size_t)rowg * 768 + colg] = f2bf(acc[i][j][r]);
        }
  } else {
    unsigned short* O = (z == 0) ? Qf : Kf;
#pragma unroll
    for (int i = 0; i < 4; i++)
#pragma unroll
      for (int j = 0; j < 4; j++)
#pragma unroll
        for (int r = 0; r < 4; r++) {
          int rowg = mb + wm * 64 + i * 16 + quad * 4 + r;
          int o = nb + wn * 64 + j * 16 + c;
          int bq = rowg >> 10, q = rowg & 1023;
          int h = o & 7, dd = o >> 3;  // head, depth (0..95)
          size_t addr =
              ((((size_t)(bq * 64 + (q >> 4)) * 8 + h) * 3 + (dd >> 5)) * 64 +
               ((q & 15) | (((dd >> 3) & 3) << 4))) * 8 + (dd & 7);
          O[addr] = f2bf(acc[i][j][r]);
        }
  }
}

// ---------------------------------------------------------------------------
// K5: attention, k-stationary. Wave owns one 16-k tile, loops 4 q-tiles
// (q-chunk = 64 q), accumulates aw-weighted head-softmax into partial[8];
// one plain store per (qc,b,k,h). grid (16 kb, 16 qc, 8 b), block 256.
// ---------------------------------------------------------------------------
__global__ __launch_bounds__(256) void attn(
    const unsigned short* __restrict__ Qf, const unsigned short* __restrict__ Kf,
    const float* __restrict__ aw, float* __restrict__ Ptp) {
  int b = blockIdx.z;
  int qc = blockIdx.y;                           // 0..15
  int kt = blockIdx.x * 4 + (threadIdx.x >> 6);  // k-tile 0..63
  int lane = threadIdx.x & 63;
  int quad = lane >> 4;
  const unsigned short* Kb =
      Kf + (size_t)(b * 64 + kt) * 12288 + (size_t)lane * 8;
  bf16x8 kfr[8][3];
#pragma unroll
  for (int h = 0; h < 8; h++)
#pragma unroll
    for (int t = 0; t < 3; t++)
      kfr[h][t] = *(const bf16x8*)(Kb + (h * 3 + t) * 512);
  float partial[8];
#pragma unroll
  for (int h = 0; h < 8; h++) partial[h] = 0.f;
  const float scale = 0.10206207261596577f;  // 1/sqrt(96)
  for (int qi = 0; qi < 4; qi++) {
    int qt = qc * 4 + qi;
    const unsigned short* Qb =
        Qf + (size_t)(b * 64 + qt) * 12288 + (size_t)lane * 8;
    f32x4 s[8];
#pragma unroll
    for (int h = 0; h < 8; h++) {
      f32x4 sh = 0;
#pragma unroll
      for (int t = 0; t < 3; t++) {
        bf16x8 qfr = *(const bf16x8*)(Qb + (h * 3 + t) * 512);
        sh = __builtin_amdgcn_mfma_f32_16x16x32_bf16(qfr, kfr[h][t], sh, 0, 0, 0);
      }
      s[h] = sh;
    }
    f32x4 al = *(const f32x4*)(aw + b * 1024 + qt * 16 + quad * 4);
#pragma unroll
    for (int r = 0; r < 4; r++) {
      float v[8], m = -1e30f;
#pragma unroll
      for (int h = 0; h < 8; h++) {
        v[h] = s[h][r] * scale;
        m = fmaxf(m, v[h]);
      }
      float ssum = 0.f;
#pragma unroll
      for (int h = 0; h < 8; h++) {
        float e = __expf(v[h] - m);
        v[h] = e;
        ssum += e;
      }
      float g = al[r] * __builtin_amdgcn_rcpf(ssum);  // aw==0 for padded q
#pragma unroll
      for (int h = 0; h < 8; h++) partial[h] += v[h] * g;
    }
  }
#pragma unroll
  for (int h = 0; h < 8; h++) {
    float v = partial[h];
    v += __shfl_xor(v, 16);
    v += __shfl_xor(v, 32);
    partial[h] = v;
  }
  if (lane < 16) {
#pragma unroll
    for (int h = 0; h < 8; h++)
      Ptp[(((size_t)qc * 8 + b) * 1024 + kt * 16 + lane) * 8 + h] = partial[h];
  }
}

// ---------------------------------------------------------------------------
// K6: out[b,o] = sum_k (sum_qc Ptp[qc][b][k][o&7]) * V[b,k,o]   (V is bf16)
// grid (8 kc, 8 b)
// ---------------------------------------------------------------------------
__global__ __launch_bounds__(256) void finalize(
    const float* __restrict__ Ptp, const unsigned short* __restrict__ Vbf,
    float* __restrict__ out) {
  __shared__ float ps[1024];  // 128 k x 8 h
  int kc = blockIdx.x, b = blockIdx.y;
  int t = threadIdx.x;
#pragma unroll
  for (int j = 0; j < 4; j++) {
    int idx = t + j * 256;
    int k = kc * 128 + (idx >> 3), h = idx & 7;
    float s = 0.f;
#pragma unroll
    for (int qc = 0; qc < 16; qc++)
      s += Ptp[(((size_t)qc * 8 + b) * 1024 + k) * 8 + h];
    ps[idx] = s;
  }
  __syncthreads();
  int h = t & 7;
  float a0 = 0, a1 = 0, a2 = 0;
  const unsigned short* Vb = Vbf + ((size_t)b * 1024 + kc * 128) * 768;
  for (int kk = 0; kk < 128; kk++) {
    float p = ps[kk * 8 + h];
    const unsigned short* vr = Vb + (size_t)kk * 768;
    a0 += p * bf2f(vr[t]);
    a1 += p * bf2f(vr[t + 256]);
    a2 += p * bf2f(vr[t + 512]);
  }
  atomicAdd(&out[b * 768 + t], a0);
  atomicAdd(&out[b * 768 + t + 256], a1);
  atomicAdd(&out[b * 768 + t + 512], a2);
}

// ---------------------------------------------------------------------------
extern "C" void kernel_launch(void* const* d_in, const int* in_sizes, int n_in,
                              void* d_out, int out_size, void* d_ws,
                              size_t ws_size, hipStream_t stream) {
  const float* emb = (const float*)d_in[0];
  const int* tags = (const int*)d_in[1];
  const float* ww = (const float*)d_in[2];
  const float* wq = (const float*)d_in[3];
  const float* wk = (const float*)d_in[4];
  const float* wv = (const float*)d_in[5];
  float* out = (float*)d_out;
  char* ws = (char*)d_ws;
  unsigned short* embbf = (unsigned short*)(ws + 0);           // 12,582,912
  unsigned short* wbf   = (unsigned short*)(ws + 12582912);    //  3,538,944
  unsigned short* Qf    = (unsigned short*)(ws + 16121856);    // 12,582,912
  unsigned short* Kf    = (unsigned short*)(ws + 28704768);    // 12,582,912
  unsigned short* Vbf   = (unsigned short*)(ws + 41287680);    // 12,582,912
  float* logits         = (float*)(ws + 53870592);             //     32,768
  float* aw             = (float*)(ws + 53903360);             //     32,768
  float* Ptp            = (float*)(ws + 53936128);             //  4,194,304

  hipMemsetAsync(out, 0, 8 * 768 * sizeof(float), stream);
  cast_emb_logits<<<2048, 256, 0, stream>>>(emb, tags, ww, embbf, logits);
  cast_w<<<dim3(576, 3), 256, 0, stream>>>(wq, wk, wv, wbf);
  softmax_aw<<<8, 256, 0, stream>>>(logits, aw);
  qkv_gemm<<<dim3(64, 6, 3), 256, 0, stream>>>(embbf, wbf, Qf, Kf, Vbf);
  attn<<<dim3(16, 16, 8), 256, 0, stream>>>(Qf, Kf, aw, Ptp);
  finalize<<<dim3(8, 8), 256, 0, stream>>>(Ptp, Vbf, out);
}

// Round 4
// 186.355 us; speedup vs baseline: 1.9546x; 1.3316x over previous
//
#include <hip/hip_runtime.h>
#include <hip/hip_bf16.h>
#include <math.h>

#define NEGV (-1e10f)

typedef __attribute__((ext_vector_type(8))) short bf16x8;
typedef __attribute__((ext_vector_type(4))) float f32x4;

static __device__ __forceinline__ unsigned short f2bf(float f) {
  unsigned int u = __builtin_bit_cast(unsigned int, f);
  unsigned int r = (u + 0x7fffu + ((u >> 16) & 1u)) >> 16;
  return (unsigned short)r;
}
static __device__ __forceinline__ float bf2f(unsigned short v) {
  return __builtin_bit_cast(float, (unsigned int)v << 16);
}

#define GLD16(g, l)                                                   \
  __builtin_amdgcn_global_load_lds(                                   \
      (const __attribute__((address_space(1))) void*)(g),             \
      (__attribute__((address_space(3))) void*)(l), 16, 0, 0)

// ---------------------------------------------------------------------------
// K1: cast emb fp32 -> bf16 AND compute attn-weight logits (dot with w_weight)
// ---------------------------------------------------------------------------
__global__ __launch_bounds__(256) void cast_emb_logits(
    const float* __restrict__ emb, const int* __restrict__ tags,
    const float* __restrict__ ww, unsigned short* __restrict__ embbf,
    float* __restrict__ logits) {
  int w = threadIdx.x >> 6, lane = threadIdx.x & 63;
  int row = blockIdx.x * 4 + w;  // 0..8191
  const float4* src = (const float4*)(emb + (size_t)row * 768);
  const float4* wsrc = (const float4*)ww;
  ushort4* dst = (ushort4*)(embbf + (size_t)row * 768);
  float d = 0.f;
#pragma unroll
  for (int j = 0; j < 3; j++) {
    int idx = lane + 64 * j;
    float4 v = src[idx];
    float4 wv = wsrc[idx];
    d += v.x * wv.x + v.y * wv.y + v.z * wv.z + v.w * wv.w;
    ushort4 o;
    o.x = f2bf(v.x); o.y = f2bf(v.y); o.z = f2bf(v.z); o.w = f2bf(v.w);
    dst[idx] = o;
  }
#pragma unroll
  for (int off = 32; off; off >>= 1) d += __shfl_xor(d, off);
  if (lane == 0) logits[row] = (tags[row] == 0) ? NEGV : d;
}

// ---------------------------------------------------------------------------
// K2: cast the three weight matrices fp32 -> bf16  [3][768][768]
// ---------------------------------------------------------------------------
__global__ __launch_bounds__(256) void cast_w(
    const float* __restrict__ wq, const float* __restrict__ wk,
    const float* __restrict__ wv, unsigned short* __restrict__ out) {
  int z = blockIdx.y;
  const float* src = (z == 0) ? wq : (z == 1) ? wk : wv;
  int idx = blockIdx.x * 256 + threadIdx.x;
  float4 v = ((const float4*)src)[idx];
  ushort4 o;
  o.x = f2bf(v.x); o.y = f2bf(v.y); o.z = f2bf(v.z); o.w = f2bf(v.w);
  ((ushort4*)(out + (size_t)z * 589824))[idx] = o;
}

// ---------------------------------------------------------------------------
// K3: softmax over s=1024 per batch of the masked logits -> aw
// ---------------------------------------------------------------------------
__global__ __launch_bounds__(256) void softmax_aw(
    const float* __restrict__ logits, float* __restrict__ aw) {
  __shared__ float red[4];
  int b = blockIdx.x, t = threadIdx.x;
  const float* L = logits + b * 1024;
  float x0 = L[t], x1 = L[t + 256], x2 = L[t + 512], x3 = L[t + 768];
  float m = fmaxf(fmaxf(x0, x1), fmaxf(x2, x3));
#pragma unroll
  for (int off = 32; off; off >>= 1) m = fmaxf(m, __shfl_xor(m, off));
  if ((t & 63) == 0) red[t >> 6] = m;
  __syncthreads();
  m = fmaxf(fmaxf(red[0], red[1]), fmaxf(red[2], red[3]));
  float e0 = __expf(x0 - m), e1 = __expf(x1 - m), e2 = __expf(x2 - m),
        e3 = __expf(x3 - m);
  float s = e0 + e1 + e2 + e3;
#pragma unroll
  for (int off = 32; off; off >>= 1) s += __shfl_xor(s, off);
  __syncthreads();
  if ((t & 63) == 0) red[t >> 6] = s;
  __syncthreads();
  float inv = 1.0f / (red[0] + red[1] + red[2] + red[3]);
  float* A = aw + b * 1024;
  A[t] = e0 * inv; A[t + 256] = e1 * inv;
  A[t + 512] = e2 * inv; A[t + 768] = e3 * inv;
}

// ---------------------------------------------------------------------------
// K4: QKV projection GEMM. 128x128 tile, BK=32, global_load_lds width=16,
// prefetch-ahead DOUBLE-BUFFERED staging with ONE barrier per K-iter.
// z=0 -> Q fragment-major bf16, z=1 -> K fragment-major bf16, z=2 -> V bf16.
// Q/K epilogue: scatter acc into LDS in fragment-packed order, then fully
// coalesced dwordx4 stores (replaces the 2B-scatter epilogue of R3).
// Fragment-major: element (b,q,h,d) chunk = ((b*64+q/16)*8+h)*3 + d/32,
//   in-chunk lane = (q%16)|(((d/8)%4)<<4), elem d%8.
// ---------------------------------------------------------------------------
__global__ __launch_bounds__(256) void qkv_gemm(
    const unsigned short* __restrict__ A, const unsigned short* __restrict__ Wbf,
    unsigned short* __restrict__ Qf, unsigned short* __restrict__ Kf,
    unsigned short* __restrict__ Vbf) {
  // union: staging (2x(128x32) x 2 mats = 16384 shorts) / epilogue repack
  // (64 runs x 264 shorts = 16896 shorts, run stride 528B = 16B-aligned)
  __shared__ __align__(16) unsigned short sm[16896];
  unsigned short* As = sm;         // dbuf: As + buf*4096
  unsigned short* Bs = sm + 8192;  // dbuf: Bs + buf*4096
  int z = blockIdx.z;
  const unsigned short* B = Wbf + (size_t)z * 589824;
  int mb = blockIdx.x * 128, nb = blockIdx.y * 128;
  int tid = threadIdx.x;
  int w = tid >> 6, lane = tid & 63;
  int wm = w >> 1, wn = w & 1;
  int c = lane & 15, quad = lane >> 4;
  // staging: wave w covers rows [w*32, w*32+32); two GLD16 calls of 16 rows.
  int lrow = lane >> 2, lcol = (lane & 3) * 8;
  const unsigned short* Ag = A + (size_t)(mb + w * 32 + lrow) * 768 + lcol;
  const unsigned short* Bg = B + (size_t)(nb + w * 32 + lrow) * 768 + lcol;
  int woff = w * 1024;  // w*32 rows * 32 cols

#define PREFETCH(buf, kb)                                              \
  do {                                                                 \
    GLD16(Ag + (kb), As + (buf) * 4096 + woff);                        \
    GLD16(Ag + (kb) + 16 * 768, As + (buf) * 4096 + woff + 512);       \
    GLD16(Bg + (kb), Bs + (buf) * 4096 + woff);                        \
    GLD16(Bg + (kb) + 16 * 768, Bs + (buf) * 4096 + woff + 512);       \
  } while (0)

  f32x4 acc[4][4];
#pragma unroll
  for (int i = 0; i < 4; i++)
#pragma unroll
    for (int j = 0; j < 4; j++) acc[i][j] = 0;

  PREFETCH(0, 0);
  for (int it = 0; it < 24; it++) {
    __syncthreads();  // all waves between barrier it and it+1 together:
                      // read buf it&1, write buf (it+1)&1 -> safe; vmcnt(0)
                      // drain here covers the prefetch issued LAST iter.
    if (it + 1 < 24) PREFETCH((it + 1) & 1, (it + 1) * 32);
    const unsigned short* Ab = As + (it & 1) * 4096;
    const unsigned short* Bb = Bs + (it & 1) * 4096;
    bf16x8 af[4], bfr[4];
#pragma unroll
    for (int i = 0; i < 4; i++)
      af[i] = *(const bf16x8*)&Ab[(wm * 64 + i * 16 + c) * 32 + quad * 8];
#pragma unroll
    for (int j = 0; j < 4; j++)
      bfr[j] = *(const bf16x8*)&Bb[(wn * 64 + j * 16 + c) * 32 + quad * 8];
#pragma unroll
    for (int i = 0; i < 4; i++)
#pragma unroll
      for (int j = 0; j < 4; j++)
        acc[i][j] = __builtin_amdgcn_mfma_f32_16x16x32_bf16(af[i], bfr[j],
                                                            acc[i][j], 0, 0, 0);
  }
  __syncthreads();  // staging reads done before epilogue reuses sm

  // C row = mb+wm*64+i*16+quad*4+r, col = nb+wn*64+j*16+c
  if (z == 2) {
#pragma unroll
    for (int i = 0; i < 4; i++)
#pragma unroll
      for (int j = 0; j < 4; j++)
#pragma unroll
        for (int r = 0; r < 4; r++) {
          int rowg = mb + wm * 64 + i * 16 + quad * 4 + r;
          int colg = nb + wn * 64 + j * 16 + c;
          Vbf[(size_t)rowg * 768 + colg] = f2bf(acc[i][j][r]);
        }
  } else {
    unsigned short* O = (z == 0) ? Qf : Kf;
    // scatter into LDS in fragment-packed order:
    // run = qt*8 + h (qt = local q-tile 0..7, h = head), 264-short stride;
    // within run: l32*8 + e, l32 = (q%16)|(dd_local>>3 <<4), e = dd_local%8
#pragma unroll
    for (int i = 0; i < 4; i++) {
      int qt = wm * 4 + i;
#pragma unroll
      for (int j = 0; j < 4; j++) {
#pragma unroll
        for (int r = 0; r < 4; r++) {
          int run = qt * 8 + (c & 7);              // h = c&7
          int l32 = (quad * 4 + r) | (wn << 4);    // dd_local>>3 = wn
          int e = j * 2 + (c >> 3);                // dd_local%8
          sm[run * 264 + l32 * 8 + e] = f2bf(acc[i][j][r]);
        }
      }
    }
    __syncthreads();
    // coalesced readout: 64 runs x 512B contiguous in Qf/Kf
    int bq = mb >> 10;             // batch index (128 | 1024)
    int qtg0 = (mb & 1023) >> 4;   // base q-tile within batch
    int tt = blockIdx.y >> 1;      // d/32 chunk index
    int halfoff = (blockIdx.y & 1) * 256;  // shorts: which 32-lane half
#pragma unroll
    for (int it2 = 0; it2 < 8; it2++) {
      int g = it2 * 256 + tid;
      int run = g >> 5, l32 = g & 31;
      int qt = run >> 3, h = run & 7;
      bf16x8 vdat = *(const bf16x8*)&sm[run * 264 + l32 * 8];
      size_t dst =
          (((size_t)(bq * 64 + qtg0 + qt) * 8 + h) * 3 + tt) * 512 +
          halfoff + l32 * 8;
      *(bf16x8*)&O[dst] = vdat;
    }
  }
#undef PREFETCH
}

// ---------------------------------------------------------------------------
// K5: attention, k-stationary. Wave owns one 16-k tile, loops 4 q-tiles
// (q-chunk = 64 q), accumulates aw-weighted head-softmax into partial[8];
// one plain store per (qc,b,k,h). grid (16 kb, 16 qc, 8 b), block 256.
// ---------------------------------------------------------------------------
__global__ __launch_bounds__(256) void attn(
    const unsigned short* __restrict__ Qf, const unsigned short* __restrict__ Kf,
    const float* __restrict__ aw, float* __restrict__ Ptp) {
  int b = blockIdx.z;
  int qc = blockIdx.y;                           // 0..15
  int kt = blockIdx.x * 4 + (threadIdx.x >> 6);  // k-tile 0..63
  int lane = threadIdx.x & 63;
  int quad = lane >> 4;
  const unsigned short* Kb =
      Kf + (size_t)(b * 64 + kt) * 12288 + (size_t)lane * 8;
  bf16x8 kfr[8][3];
#pragma unroll
  for (int h = 0; h < 8; h++)
#pragma unroll
    for (int t = 0; t < 3; t++)
      kfr[h][t] = *(const bf16x8*)(Kb + (h * 3 + t) * 512);
  float partial[8];
#pragma unroll
  for (int h = 0; h < 8; h++) partial[h] = 0.f;
  const float scale = 0.10206207261596577f;  // 1/sqrt(96)
  for (int qi = 0; qi < 4; qi++) {
    int qt = qc * 4 + qi;
    const unsigned short* Qb =
        Qf + (size_t)(b * 64 + qt) * 12288 + (size_t)lane * 8;
    f32x4 s[8];
#pragma unroll
    for (int h = 0; h < 8; h++) {
      f32x4 sh = 0;
#pragma unroll
      for (int t = 0; t < 3; t++) {
        bf16x8 qfr = *(const bf16x8*)(Qb + (h * 3 + t) * 512);
        sh = __builtin_amdgcn_mfma_f32_16x16x32_bf16(qfr, kfr[h][t], sh, 0, 0, 0);
      }
      s[h] = sh;
    }
    f32x4 al = *(const f32x4*)(aw + b * 1024 + qt * 16 + quad * 4);
#pragma unroll
    for (int r = 0; r < 4; r++) {
      float v[8], m = -1e30f;
#pragma unroll
      for (int h = 0; h < 8; h++) {
        v[h] = s[h][r] * scale;
        m = fmaxf(m, v[h]);
      }
      float ssum = 0.f;
#pragma unroll
      for (int h = 0; h < 8; h++) {
        float e = __expf(v[h] - m);
        v[h] = e;
        ssum += e;
      }
      float g = al[r] * __builtin_amdgcn_rcpf(ssum);  // aw==0 for padded q
#pragma unroll
      for (int h = 0; h < 8; h++) partial[h] += v[h] * g;
    }
  }
#pragma unroll
  for (int h = 0; h < 8; h++) {
    float v = partial[h];
    v += __shfl_xor(v, 16);
    v += __shfl_xor(v, 32);
    partial[h] = v;
  }
  if (lane < 16) {
#pragma unroll
    for (int h = 0; h < 8; h++)
      Ptp[(((size_t)qc * 8 + b) * 1024 + kt * 16 + lane) * 8 + h] = partial[h];
  }
}

// ---------------------------------------------------------------------------
// K6: out[b,o] = sum_k (sum_qc Ptp[qc][b][k][o&7]) * V[b,k,o]   (V is bf16)
// grid (8 kc, 8 b)
// ---------------------------------------------------------------------------
__global__ __launch_bounds__(256) void finalize(
    const float* __restrict__ Ptp, const unsigned short* __restrict__ Vbf,
    float* __restrict__ out) {
  __shared__ float ps[1024];  // 128 k x 8 h
  int kc = blockIdx.x, b = blockIdx.y;
  int t = threadIdx.x;
#pragma unroll
  for (int j = 0; j < 4; j++) {
    int idx = t + j * 256;
    int k = kc * 128 + (idx >> 3), h = idx & 7;
    float s = 0.f;
#pragma unroll
    for (int qc = 0; qc < 16; qc++)
      s += Ptp[(((size_t)qc * 8 + b) * 1024 + k) * 8 + h];
    ps[idx] = s;
  }
  __syncthreads();
  int h = t & 7;
  float a0 = 0, a1 = 0, a2 = 0;
  const unsigned short* Vb = Vbf + ((size_t)b * 1024 + kc * 128) * 768;
  for (int kk = 0; kk < 128; kk++) {
    float p = ps[kk * 8 + h];
    const unsigned short* vr = Vb + (size_t)kk * 768;
    a0 += p * bf2f(vr[t]);
    a1 += p * bf2f(vr[t + 256]);
    a2 += p * bf2f(vr[t + 512]);
  }
  atomicAdd(&out[b * 768 + t], a0);
  atomicAdd(&out[b * 768 + t + 256], a1);
  atomicAdd(&out[b * 768 + t + 512], a2);
}

// ---------------------------------------------------------------------------
extern "C" void kernel_launch(void* const* d_in, const int* in_sizes, int n_in,
                              void* d_out, int out_size, void* d_ws,
                              size_t ws_size, hipStream_t stream) {
  const float* emb = (const float*)d_in[0];
  const int* tags = (const int*)d_in[1];
  const float* ww = (const float*)d_in[2];
  const float* wq = (const float*)d_in[3];
  const float* wk = (const float*)d_in[4];
  const float* wv = (const float*)d_in[5];
  float* out = (float*)d_out;
  char* ws = (char*)d_ws;
  unsigned short* embbf = (unsigned short*)(ws + 0);           // 12,582,912
  unsigned short* wbf   = (unsigned short*)(ws + 12582912);    //  3,538,944
  unsigned short* Qf    = (unsigned short*)(ws + 16121856);    // 12,582,912
  unsigned short* Kf    = (unsigned short*)(ws + 28704768);    // 12,582,912
  unsigned short* Vbf   = (unsigned short*)(ws + 41287680);    // 12,582,912
  float* logits         = (float*)(ws + 53870592);             //     32,768
  float* aw             = (float*)(ws + 53903360);             //     32,768
  float* Ptp            = (float*)(ws + 53936128);             //  4,194,304

  hipMemsetAsync(out, 0, 8 * 768 * sizeof(float), stream);
  cast_emb_logits<<<2048, 256, 0, stream>>>(emb, tags, ww, embbf, logits);
  cast_w<<<dim3(576, 3), 256, 0, stream>>>(wq, wk, wv, wbf);
  softmax_aw<<<8, 256, 0, stream>>>(logits, aw);
  qkv_gemm<<<dim3(64, 6, 3), 256, 0, stream>>>(embbf, wbf, Qf, Kf, Vbf);
  attn<<<dim3(16, 16, 8), 256, 0, stream>>>(Qf, Kf, aw, Ptp);
  finalize<<<dim3(8, 8), 256, 0, stream>>>(Ptp, Vbf, out);
}